// Round 15
// baseline (270.315 us; speedup 1.0000x reference)
//
#include <hip/hip_runtime.h>

#define NB 32
#define NS 512
#define NE 128
#define NU 10000

typedef __attribute__((ext_vector_type(8))) short bf16x8;
typedef __attribute__((ext_vector_type(4))) float f32x4;

__device__ __forceinline__ unsigned short f2bf(float f) {
    unsigned int u = __float_as_uint(f);
    u += 0x7fff + ((u >> 16) & 1);   // round-to-nearest-even
    return (unsigned short)(u >> 16);
}

// LDS-only barrier (no vmcnt drain; global loads/stores stay in flight).
#define BARRIER() do { \
    asm volatile("s_waitcnt lgkmcnt(0)" ::: "memory"); \
    __builtin_amdgcn_s_barrier(); \
    __builtin_amdgcn_sched_barrier(0); \
} while (0)

// ONE kernel, one block per batch b (32 blocks x 512 threads). Everything —
// prep, all GRU rounds, deep chains — stays inside the block: no workspace,
// no cross-block deps, no extra dispatches. Phases (r0, r1, r2) use the
// T14 pipeline (next chunk's meta+gather issued under current MFMA/gates);
// phase boundaries use threadfence+syncthreads (~3 per block, cheap).
// Late nodes (depth>2, ~0-2 per block) run serially in t-order, fenced.
__global__ __launch_bounds__(512, 1) void limnet_all(
    const int* __restrict__ users, const int* __restrict__ items,
    const float* __restrict__ umem0, const float* __restrict__ imem0,
    const float* __restrict__ w_ih, const float* __restrict__ w_hh,
    const float* __restrict__ b_ih, const float* __restrict__ b_hh,
    float* uout, float* iout)
{
    const int b = blockIdx.x, tid = threadIdx.x;
    const int lane = tid & 63, wave = tid >> 6;
    const int col = lane & 15, kgrp = lane >> 4;

    __shared__ __align__(16) float yl[16 * 1156];          // 74.0 KB
    __shared__ __align__(16) float xf[16 * 132];           // 8.4 KB
    __shared__ __align__(16) unsigned short xb[16 * 136];  // 4.4 KB
    __shared__ float b6[768];
    __shared__ int s_u[NS], s_i[NS];
    __shared__ short s_pU[NS], s_pI[NS];
    __shared__ unsigned char s_r[NS];
    __shared__ short s_list[4][NS];                        // r0,r1,r2,late
    __shared__ int s_cnt[4], s_chg;
    __shared__ unsigned long long srcs[2][16];
    __shared__ unsigned long long hdst[2][16];

    s_u[tid] = users[b * NS + tid];
    s_i[tid] = items[b * NS + tid];
    if (tid < 4) s_cnt[tid] = 0;
    for (int i = tid; i < 768; i += 512)
        b6[i] = i < 384 ? b_ih[i] : b_hh[i - 384];

    // ---- W_stack (1152x128) -> bf16 MFMA A-fragments, direct from global.
    // row R: R<384 -> w_ih[R,0:128]; R<768 -> w_ih[R-384,128:256]; else
    // w_hh[R-768,:]. Lane holds A[row=col][k=kt*32+kgrp*8+j].
    bf16x8 wfrag[9][4];
#pragma unroll
    for (int m9 = 0; m9 < 9; ++m9) {
        const int row = wave * 144 + m9 * 16 + col;
#pragma unroll
        for (int kt = 0; kt < 4; ++kt) {
            const int k = kt * 32 + kgrp * 8;
            const float* src;
            if (row < 384)      src = w_ih + (size_t)row * 256 + k;
            else if (row < 768) src = w_ih + (size_t)(row - 384) * 256 + 128 + k;
            else                src = w_hh + (size_t)(row - 768) * 128 + k;
            const float4 f0 = *(const float4*)(src);
            const float4 f1 = *(const float4*)(src + 4);
            bf16x8 wv;
            wv[0] = (short)f2bf(f0.x); wv[1] = (short)f2bf(f0.y);
            wv[2] = (short)f2bf(f0.z); wv[3] = (short)f2bf(f0.w);
            wv[4] = (short)f2bf(f1.x); wv[5] = (short)f2bf(f1.y);
            wv[6] = (short)f2bf(f1.z); wv[7] = (short)f2bf(f1.w);
            wfrag[m9][kt] = wv;
        }
    }
    __syncthreads();

    // ---- dual backward prev-scan, interleaved (16 indep LDS reads/iter) ----
    const int mu = s_u[tid], mi = s_i[tid];
    int pu = -1, pi = -1;
    for (int u = tid - 1; u >= 0 && ((pu < 0) | (pi < 0)); u -= 8) {
        int vu[8], vi[8];
#pragma unroll
        for (int j = 0; j < 8; ++j) {
            const int uu = u - j;
            vu[j] = (uu >= 0) ? s_u[uu] : -1;
            vi[j] = (uu >= 0) ? s_i[uu] : -1;
        }
#pragma unroll
        for (int j = 0; j < 8; ++j) {
            if (pu < 0 && vu[j] == mu) pu = u - j;
            if (pi < 0 && vi[j] == mi) pi = u - j;
        }
    }
    s_pU[tid] = (short)pu;
    s_pI[tid] = (short)pi;
    // ---- round relaxation: 0,1,2 batched rounds; >=3 or unresolved: late ----
    s_r[tid] = (pu < 0 && pi < 0) ? 0 : 255;
    __syncthreads();
    for (int pass = 0; pass < 16; ++pass) {
        if (tid == 0) s_chg = 0;
        __syncthreads();
        if (s_r[tid] == 255) {
            const int ru = pu < 0 ? -1 : (int)s_r[pu];
            const int ri = pi < 0 ? -1 : (int)s_r[pi];
            if (ru != 255 && ri != 255) {
                int rr = 1 + (ru > ri ? ru : ri);
                if (rr > 3) rr = 3;
                s_r[tid] = (unsigned char)rr;
                s_chg = 1;
            }
        }
        __syncthreads();
        if (!s_chg) break;
    }
    {
        const int r = s_r[tid];
        if (r < 3) {
            const int slot = atomicAdd(&s_cnt[r], 1);
            s_list[r][slot] = (short)tid;
        }
    }
    __syncthreads();
    if (tid == 0) {   // late list in t-order (handles any depth)
        int n = 0;
        for (int t = 0; t < NS; ++t)
            if (s_r[t] >= 3) { s_list[3][n] = (short)t; ++n; }
        s_cnt[3] = n;
    }
    __syncthreads();

    const int gc = tid >> 5, ge4 = (tid & 31) * 4;

#define META(PH, LC, SEL) do { \
    if (tid < 16) { \
        const int j = (LC) * 8 + (tid >> 1); \
        unsigned long long sp = 0, hd = 0; \
        if (j < s_cnt[PH]) { \
            const int t = (int)s_list[PH][j]; \
            const int node = (b << 9) + t; \
            const int cell = tid & 1; \
            const int p = cell ? (int)s_pI[t] : (int)s_pU[t]; \
            const float* s; \
            if (p < 0) { \
                const int ix = cell ? s_i[t] : s_u[t]; \
                s = (cell ? imem0 : umem0) + ((size_t)b * NU + ix) * NE; \
            } else { \
                s = (cell ? iout : uout) + ((size_t)((b << 9) + p)) * NE; \
            } \
            sp = (unsigned long long)s; \
            hd = (unsigned long long)((cell ? iout : uout) + (size_t)node * NE); \
        } \
        srcs[SEL][tid] = sp; hdst[SEL][tid] = hd; \
    } \
} while (0)

    // ---- phases 0,1,2: pipelined chunk processing ----
    for (int ph = 0; ph < 3; ++ph) {
        const int nch = (s_cnt[ph] + 7) >> 3;
        if (nch > 0) {
            int cur = 0;
            META(ph, 0, 0);
            BARRIER();
            float4 v = (float4){0.f, 0.f, 0.f, 0.f};
            {
                const float* s = (const float*)srcs[0][gc];
                if (s) v = *(const float4*)(s + ge4);
            }
            for (int lc = 0; lc < nch; ++lc) {
                const int nxt = cur ^ 1;
                const bool hasnext = (lc + 1) < nch;
                if (hasnext) META(ph, lc + 1, nxt);
                if (hdst[cur][gc]) {        // stage current chunk x
                    *(float4*)&xf[gc * 132 + ge4] = v;
                    ushort4 w4;
                    w4.x = f2bf(v.x); w4.y = f2bf(v.y);
                    w4.z = f2bf(v.z); w4.w = f2bf(v.w);
                    *(ushort4*)&xb[gc * 136 + ge4] = w4;
                }
                BARRIER();                  // xb/xf + srcs[nxt] visible
                float4 vn = (float4){0.f, 0.f, 0.f, 0.f};
                if (hasnext) {              // gather retires under MFMA+gates
                    const float* s = (const float*)srcs[nxt][gc];
                    if (s) vn = *(const float4*)(s + ge4);
                }
                {   // MFMA: y[16 cols][1152] = W @ X
                    bf16x8 bfrag[4];
#pragma unroll
                    for (int kt = 0; kt < 4; ++kt)
                        bfrag[kt] = *(const bf16x8*)&xb[col * 136 + kt * 32 + kgrp * 8];
                    f32x4 acc[9];
#pragma unroll
                    for (int m9 = 0; m9 < 9; ++m9)
                        acc[m9] = (f32x4){0.f, 0.f, 0.f, 0.f};
#pragma unroll
                    for (int kt = 0; kt < 4; ++kt)
#pragma unroll
                        for (int m9 = 0; m9 < 9; ++m9)
                            acc[m9] = __builtin_amdgcn_mfma_f32_16x16x32_bf16(
                                wfrag[m9][kt], bfrag[kt], acc[m9], 0, 0, 0);
#pragma unroll
                    for (int m9 = 0; m9 < 9; ++m9)  // D: col=lane&15, row=kgrp*4+reg
                        *(f32x4*)&yl[col * 1156 + wave * 144 + m9 * 16 + kgrp * 4] = acc[m9];
                }
                BARRIER();
#pragma unroll
                for (int it = 0; it < 4; ++it) {    // gates + h scatter
                    const int idx = tid + it * 512;
                    const int c = idx >> 7, e = idx & 127;
                    float* hb = (float*)hdst[cur][c];
                    if (hb) {
                        const float* ys = &yl[c * 1156];
                        const float* yo = &yl[(c ^ 1) * 1156];
                        const float gir = ys[e]        + yo[384 + e] + b6[e];
                        const float giz = ys[128 + e]  + yo[512 + e] + b6[128 + e];
                        const float gin = ys[256 + e]  + yo[640 + e] + b6[256 + e];
                        const float ghr = ys[768 + e]  + b6[384 + e];
                        const float ghz = ys[896 + e]  + b6[512 + e];
                        const float ghn = ys[1024 + e] + b6[640 + e];
                        const float rr = 1.f / (1.f + __expf(-(gir + ghr)));
                        const float z  = 1.f / (1.f + __expf(-(giz + ghz)));
                        const float pre = gin + rr * ghn;
                        const float nn = 2.f / (1.f + __expf(-2.f * pre)) - 1.f;
                        hb[e] = (1.f - z) * nn + z * xf[c * 132 + e];
                    }
                }
                BARRIER();
                v = vn; cur = nxt;
            }
        }
        __threadfence();    // phase boundary: h of this phase visible
        __syncthreads();
    }

    // ---- late phase: serial in t-order (any depth), fenced per node ----
    const int nL = s_cnt[3];
    for (int k = 0; k < nL; ++k) {
        if (tid < 16) {
            unsigned long long sp = 0, hd = 0;
            if (tid < 2) {
                const int t = (int)s_list[3][k];
                const int node = (b << 9) + t;
                const int cell = tid;
                const int p = cell ? (int)s_pI[t] : (int)s_pU[t];
                const float* s;
                if (p < 0) {
                    const int ix = cell ? s_i[t] : s_u[t];
                    s = (cell ? imem0 : umem0) + ((size_t)b * NU + ix) * NE;
                } else {
                    s = (cell ? iout : uout) + ((size_t)((b << 9) + p)) * NE;
                }
                sp = (unsigned long long)s;
                hd = (unsigned long long)((cell ? iout : uout) + (size_t)node * NE);
            }
            srcs[0][tid] = sp; hdst[0][tid] = hd;
        }
        __syncthreads();
        {
            const float* s = (const float*)srcs[0][gc];
            if (s) {
                const float4 vv = *(const float4*)(s + ge4);
                *(float4*)&xf[gc * 132 + ge4] = vv;
                ushort4 w4;
                w4.x = f2bf(vv.x); w4.y = f2bf(vv.y);
                w4.z = f2bf(vv.z); w4.w = f2bf(vv.w);
                *(ushort4*)&xb[gc * 136 + ge4] = w4;
            }
        }
        __syncthreads();
        {
            bf16x8 bfrag[4];
#pragma unroll
            for (int kt = 0; kt < 4; ++kt)
                bfrag[kt] = *(const bf16x8*)&xb[col * 136 + kt * 32 + kgrp * 8];
            f32x4 acc[9];
#pragma unroll
            for (int m9 = 0; m9 < 9; ++m9) acc[m9] = (f32x4){0.f, 0.f, 0.f, 0.f};
#pragma unroll
            for (int kt = 0; kt < 4; ++kt)
#pragma unroll
                for (int m9 = 0; m9 < 9; ++m9)
                    acc[m9] = __builtin_amdgcn_mfma_f32_16x16x32_bf16(
                        wfrag[m9][kt], bfrag[kt], acc[m9], 0, 0, 0);
#pragma unroll
            for (int m9 = 0; m9 < 9; ++m9)
                *(f32x4*)&yl[col * 1156 + wave * 144 + m9 * 16 + kgrp * 4] = acc[m9];
        }
        __syncthreads();
#pragma unroll
        for (int it = 0; it < 4; ++it) {
            const int idx = tid + it * 512;
            const int c = idx >> 7, e = idx & 127;
            float* hb = (float*)hdst[0][c];
            if (hb) {
                const float* ys = &yl[c * 1156];
                const float* yo = &yl[(c ^ 1) * 1156];
                const float gir = ys[e]        + yo[384 + e] + b6[e];
                const float giz = ys[128 + e]  + yo[512 + e] + b6[128 + e];
                const float gin = ys[256 + e]  + yo[640 + e] + b6[256 + e];
                const float ghr = ys[768 + e]  + b6[384 + e];
                const float ghz = ys[896 + e]  + b6[512 + e];
                const float ghn = ys[1024 + e] + b6[640 + e];
                const float rr = 1.f / (1.f + __expf(-(gir + ghr)));
                const float z  = 1.f / (1.f + __expf(-(giz + ghz)));
                const float pre = gin + rr * ghn;
                const float nn = 2.f / (1.f + __expf(-2.f * pre)) - 1.f;
                hb[e] = (1.f - z) * nn + z * xf[c * 132 + e];
            }
        }
        __threadfence();
        __syncthreads();
    }
#undef META
}

extern "C" void kernel_launch(void* const* d_in, const int* in_sizes, int n_in,
                              void* d_out, int out_size, void* d_ws, size_t ws_size,
                              hipStream_t stream) {
    const int*   users = (const int*)d_in[0];
    const int*   items = (const int*)d_in[1];
    const float* umem0 = (const float*)d_in[2];
    const float* imem0 = (const float*)d_in[3];
    const float* w_ih  = (const float*)d_in[4];
    const float* w_hh  = (const float*)d_in[5];
    const float* b_ih  = (const float*)d_in[6];
    const float* b_hh  = (const float*)d_in[7];

    float* uout = (float*)d_out;
    float* iout = uout + (size_t)NB * NS * NE;

    limnet_all<<<NB, 512, 0, stream>>>(users, items, umem0, imem0,
                                       w_ih, w_hh, b_ih, b_hh, uout, iout);
}

// Round 16
// 197.976 us; speedup vs baseline: 1.3654x; 1.3654x over previous
//
#include <hip/hip_runtime.h>

#define NB 32
#define NS 512
#define NE 128
#define NU 10000

// ---- workspace layout (int units) ----
#define WS_PREVU 0                 // 16384
#define WS_PREVI 16384             // 16384
#define WS_RCNT  32768             // 3*32 per-(round,b) counts
#define WS_LCNT  32864             // 32 per-b late counts
#define WS_BAR   32896             // 2 grid-barrier counters
#define WS_GL    32912             // 3*32*512 per-(round,b) t-lists
#define WS_LATE  82064             // 32*512 per-b late t-lists
#define WS_WBF   98448             // 147456 ushorts (bf16 W_stack)

typedef __attribute__((ext_vector_type(8))) short bf16x8;
typedef __attribute__((ext_vector_type(4))) float f32x4;

__device__ __forceinline__ unsigned short f2bf(float f) {
    unsigned int u = __float_as_uint(f);
    u += 0x7fff + ((u >> 16) & 1);   // round-to-nearest-even
    return (unsigned short)(u >> 16);
}

// LDS-only barrier (no vmcnt drain; global loads/stores stay in flight).
#define BARRIER() do { \
    asm volatile("s_waitcnt lgkmcnt(0)" ::: "memory"); \
    __builtin_amdgcn_s_barrier(); \
    __builtin_amdgcn_sched_barrier(0); \
} while (0)

// Grid-wide barrier (R12-validated sync recipe, used exactly twice).
// Counter zeroed by the PRIOR dispatch -> no init race, replay-safe.
__device__ __forceinline__ void grid_barrier(int* ctr) {
    __syncthreads();
    if (threadIdx.x == 0) {
        __threadfence();                       // release: drain + publish
        atomicAdd(ctr, 1);
        int spins = 0;
        while (atomicAdd(ctr, 0) < 256) {
            __builtin_amdgcn_s_sleep(8);
            if (++spins > (1 << 20)) break;    // failsafe (never hit)
        }
    }
    __syncthreads();
    __threadfence();                           // acquire: re-read fresh
}

// ---- kernel 1: prep (blocks 0..31) + convw (32..67) + counter zero ----
__global__ __launch_bounds__(512) void prep_kernel(
    const int* __restrict__ users, const int* __restrict__ items,
    const float* __restrict__ w_ih, const float* __restrict__ w_hh, int* ws)
{
    const int blk = blockIdx.x, tid = threadIdx.x;
    if (blk >= 32) {
        if (blk == 32 && tid < 2) ws[WS_BAR + tid] = 0;
        const int base = (blk - 32) * 4096 + tid * 8;
        const int r = base >> 7, k = base & 127;
        const float* src;
        if (r < 384)      src = w_ih + (size_t)r * 256 + k;
        else if (r < 768) src = w_ih + (size_t)(r - 384) * 256 + 128 + k;
        else              src = w_hh + (size_t)(r - 768) * 128 + k;
        unsigned short* wbf = (unsigned short*)(ws + WS_WBF);
#pragma unroll
        for (int j = 0; j < 8; ++j) wbf[base + j] = f2bf(src[j]);
        return;
    }
    const int b = blk;
    __shared__ int s_u[NS], s_i[NS];
    __shared__ unsigned char s_r[NS];
    __shared__ int cnt[3], s_chg;
    s_u[tid] = users[b * NS + tid];
    s_i[tid] = items[b * NS + tid];
    if (tid < 3) cnt[tid] = 0;
    __syncthreads();
    // dual backward scan, interleaved (16 indep LDS reads/iter)
    const int mu = s_u[tid], mi = s_i[tid];
    int pu = -1, pi = -1;
    for (int u = tid - 1; u >= 0 && ((pu < 0) | (pi < 0)); u -= 8) {
        int vu[8], vi[8];
#pragma unroll
        for (int j = 0; j < 8; ++j) {
            const int uu = u - j;
            vu[j] = (uu >= 0) ? s_u[uu] : -1;
            vi[j] = (uu >= 0) ? s_i[uu] : -1;
        }
#pragma unroll
        for (int j = 0; j < 8; ++j) {
            if (pu < 0 && vu[j] == mu) pu = u - j;
            if (pi < 0 && vi[j] == mi) pi = u - j;
        }
    }
    ws[WS_PREVU + (b << 9) + tid] = pu;
    ws[WS_PREVI + (b << 9) + tid] = pi;
    s_r[tid] = (pu < 0 && pi < 0) ? 0 : 255;
    __syncthreads();
    for (int pass = 0; pass < 16; ++pass) {
        if (tid == 0) s_chg = 0;
        __syncthreads();
        if (s_r[tid] == 255) {
            const int ru = pu < 0 ? -1 : (int)s_r[pu];
            const int ri = pi < 0 ? -1 : (int)s_r[pi];
            if (ru != 255 && ri != 255) {
                int rr = 1 + (ru > ri ? ru : ri);
                if (rr > 3) rr = 3;
                s_r[tid] = (unsigned char)rr;
                s_chg = 1;
            }
        }
        __syncthreads();
        if (!s_chg) break;
    }
    const int r = s_r[tid];
    if (r < 3) {
        const int slot = atomicAdd(&cnt[r], 1);
        ws[WS_GL + (r * 32 + b) * 512 + slot] = tid;
    }
    __syncthreads();
    if (tid < 3) ws[WS_RCNT + tid * 32 + b] = cnt[tid];
    if (tid == 0) {
        int n = 0;
        for (int t = 0; t < NS; ++t)
            if (s_r[t] >= 3) { ws[WS_LATE + (b << 9) + n] = t; ++n; }
        ws[WS_LCNT + b] = n;
    }
}

// ---- kernel 2: persistent solve — r0 || bar || r1 || bar || per-b tail ----
__global__ __launch_bounds__(512, 1) void solve_kernel(
    const int* __restrict__ users, const int* __restrict__ items,
    const float* __restrict__ umem0, const float* __restrict__ imem0,
    const float* __restrict__ b_ih, const float* __restrict__ b_hh,
    int* ws, float* uout, float* iout)
{
    const int blk = blockIdx.x, tid = threadIdx.x;
    const int lane = tid & 63, wave = tid >> 6;
    const int col = lane & 15, kgrp = lane >> 4;

    __shared__ __align__(16) float yl[16 * 1156];
    __shared__ __align__(16) float xf[16 * 132];
    __shared__ __align__(16) unsigned short xb[16 * 136];
    __shared__ float b6[768];
    __shared__ unsigned long long srcs[2][16];
    __shared__ unsigned long long hdst[2][16];

    for (int i = tid; i < 768; i += 512)
        b6[i] = i < 384 ? b_ih[i] : b_hh[i - 384];

    const unsigned short* wbf = (const unsigned short*)(ws + WS_WBF);
    bf16x8 wfrag[9][4];
#pragma unroll
    for (int m9 = 0; m9 < 9; ++m9) {
        const int row = wave * 144 + m9 * 16 + col;
#pragma unroll
        for (int kt = 0; kt < 4; ++kt)
            wfrag[m9][kt] = *(const bf16x8*)&wbf[row * 128 + kt * 32 + kgrp * 8];
    }
    __syncthreads();

    const int b = blk & 31, sblk = blk >> 5;
    const int gc = tid >> 5, ge4 = (tid & 31) * 4;
    const int* prevU = ws + WS_PREVU + (b << 9);
    const int* prevI = ws + WS_PREVI + (b << 9);

#define META(GLIST, CNT, LC, SEL) do { \
    if (tid < 16) { \
        const int j = (LC) * 8 + (tid >> 1); \
        unsigned long long sp = 0, hd = 0; \
        if (j < (CNT)) { \
            const int t = (GLIST)[j]; \
            const int node = (b << 9) + t; \
            const int cell = tid & 1; \
            const int p = cell ? prevI[t] : prevU[t]; \
            const float* s; \
            if (p < 0) { \
                const int ix = cell ? items[node] : users[node]; \
                s = (cell ? imem0 : umem0) + ((size_t)b * NU + ix) * NE; \
            } else { \
                s = (cell ? iout : uout) + ((size_t)((b << 9) + p)) * NE; \
            } \
            sp = (unsigned long long)s; \
            hd = (unsigned long long)((cell ? iout : uout) + (size_t)node * NE); \
        } \
        srcs[SEL][tid] = sp; hdst[SEL][tid] = hd; \
    } \
} while (0)

#define CHUNK_COMPUTE(CUR) do { \
    { \
        bf16x8 bfrag[4]; \
        _Pragma("unroll") \
        for (int kt = 0; kt < 4; ++kt) \
            bfrag[kt] = *(const bf16x8*)&xb[col * 136 + kt * 32 + kgrp * 8]; \
        f32x4 acc[9]; \
        _Pragma("unroll") \
        for (int m9 = 0; m9 < 9; ++m9) acc[m9] = (f32x4){0.f, 0.f, 0.f, 0.f}; \
        _Pragma("unroll") \
        for (int kt = 0; kt < 4; ++kt) \
            _Pragma("unroll") \
            for (int m9 = 0; m9 < 9; ++m9) \
                acc[m9] = __builtin_amdgcn_mfma_f32_16x16x32_bf16( \
                    wfrag[m9][kt], bfrag[kt], acc[m9], 0, 0, 0); \
        _Pragma("unroll") \
        for (int m9 = 0; m9 < 9; ++m9) \
            *(f32x4*)&yl[col * 1156 + wave * 144 + m9 * 16 + kgrp * 4] = acc[m9]; \
    } \
    BARRIER(); \
    _Pragma("unroll") \
    for (int it = 0; it < 4; ++it) { \
        const int idx = tid + it * 512; \
        const int c = idx >> 7, e = idx & 127; \
        float* hb = (float*)hdst[CUR][c]; \
        if (hb) { \
            const float* ys = &yl[c * 1156]; \
            const float* yo = &yl[(c ^ 1) * 1156]; \
            const float gir = ys[e]        + yo[384 + e] + b6[e]; \
            const float giz = ys[128 + e]  + yo[512 + e] + b6[128 + e]; \
            const float gin = ys[256 + e]  + yo[640 + e] + b6[256 + e]; \
            const float ghr = ys[768 + e]  + b6[384 + e]; \
            const float ghz = ys[896 + e]  + b6[512 + e]; \
            const float ghn = ys[1024 + e] + b6[640 + e]; \
            const float rr = 1.f / (1.f + __expf(-(gir + ghr))); \
            const float z  = 1.f / (1.f + __expf(-(giz + ghz))); \
            const float pre = gin + rr * ghn; \
            const float nn = 2.f / (1.f + __expf(-2.f * pre)) - 1.f; \
            hb[e] = (1.f - z) * nn + z * xf[c * 132 + e]; \
        } \
    } \
    BARRIER(); \
} while (0)

    // ---- rounds 0 and 1, full 256-block width, T14-pipelined ----
    for (int r = 0; r < 2; ++r) {
        const int cnt = ws[WS_RCNT + r * 32 + b];
        const int nch = (cnt + 7) >> 3;
        const int* glist = ws + WS_GL + (r * 32 + b) * 512;
        if (sblk < nch) {
            int cur = 0;
            META(glist, cnt, sblk, 0);
            BARRIER();
            float4 v = (float4){0.f, 0.f, 0.f, 0.f};
            {
                const float* s = (const float*)srcs[0][gc];
                if (s) v = *(const float4*)(s + ge4);
            }
            for (int lc = sblk; lc < nch; lc += 8) {
                const int nxt = cur ^ 1;
                const bool hasnext = (lc + 8) < nch;
                if (hasnext) META(glist, cnt, lc + 8, nxt);
                if (hdst[cur][gc]) {
                    *(float4*)&xf[gc * 132 + ge4] = v;
                    ushort4 w4;
                    w4.x = f2bf(v.x); w4.y = f2bf(v.y);
                    w4.z = f2bf(v.z); w4.w = f2bf(v.w);
                    *(ushort4*)&xb[gc * 136 + ge4] = w4;
                }
                BARRIER();
                float4 vn = (float4){0.f, 0.f, 0.f, 0.f};
                if (hasnext) {
                    const float* s = (const float*)srcs[nxt][gc];
                    if (s) vn = *(const float4*)(s + ge4);
                }
                CHUNK_COMPUTE(cur);
                v = vn; cur = nxt;
            }
        }
        grid_barrier(ws + WS_BAR + r);   // round r fully visible device-wide
    }

    // ---- tail: blocks 0..31 run r2 chunks + late singles for b = blk ----
    if (blk >= 32) return;
    const int cnt2 = ws[WS_RCNT + 64 + b];
    const int cntL = ws[WS_LCNT + b];
    for (int ph = 0; ph < 2; ++ph) {
        const int cntn = ph == 0 ? cnt2 : cntL;
        const int* lst = ph == 0 ? ws + WS_GL + (64 + b) * 512
                                 : ws + WS_LATE + (b << 9);
        const int step = ph == 0 ? 8 : 1;
        for (int j0 = 0; j0 < cntn; j0 += step) {
            const int n = (cntn - j0 < step) ? (cntn - j0) : step;
            if (tid < 16) {
                const int jj = tid >> 1;
                unsigned long long sp = 0, hd = 0;
                if (jj < n) {
                    const int t = lst[j0 + jj];
                    const int node = (b << 9) + t;
                    const int cell = tid & 1;
                    const int p = cell ? prevI[t] : prevU[t];
                    const float* s;
                    if (p < 0) {
                        const int ix = cell ? items[node] : users[node];
                        s = (cell ? imem0 : umem0) + ((size_t)b * NU + ix) * NE;
                    } else {
                        s = (cell ? iout : uout) + ((size_t)((b << 9) + p)) * NE;
                    }
                    sp = (unsigned long long)s;
                    hd = (unsigned long long)((cell ? iout : uout) + (size_t)node * NE);
                }
                srcs[0][tid] = sp; hdst[0][tid] = hd;
            }
            __syncthreads();
            {
                const float* s = (const float*)srcs[0][gc];
                if (s) {
                    const float4 vv = *(const float4*)(s + ge4);
                    *(float4*)&xf[gc * 132 + ge4] = vv;
                    ushort4 w4;
                    w4.x = f2bf(vv.x); w4.y = f2bf(vv.y);
                    w4.z = f2bf(vv.z); w4.w = f2bf(vv.w);
                    *(ushort4*)&xb[gc * 136 + ge4] = w4;
                }
            }
            __syncthreads();
            CHUNK_COMPUTE(0);
            __threadfence();     // same-block parent for next late node
            __syncthreads();
        }
    }
#undef META
#undef CHUNK_COMPUTE
}

extern "C" void kernel_launch(void* const* d_in, const int* in_sizes, int n_in,
                              void* d_out, int out_size, void* d_ws, size_t ws_size,
                              hipStream_t stream) {
    const int*   users = (const int*)d_in[0];
    const int*   items = (const int*)d_in[1];
    const float* umem0 = (const float*)d_in[2];
    const float* imem0 = (const float*)d_in[3];
    const float* w_ih  = (const float*)d_in[4];
    const float* w_hh  = (const float*)d_in[5];
    const float* b_ih  = (const float*)d_in[6];
    const float* b_hh  = (const float*)d_in[7];

    float* uout = (float*)d_out;
    float* iout = uout + (size_t)NB * NS * NE;
    int* ws = (int*)d_ws;

    prep_kernel<<<68, 512, 0, stream>>>(users, items, w_ih, w_hh, ws);
    solve_kernel<<<256, 512, 0, stream>>>(users, items, umem0, imem0,
                                          b_ih, b_hh, ws, uout, iout);
}

// Round 17
// 123.234 us; speedup vs baseline: 2.1935x; 1.6065x over previous
//
#include <hip/hip_runtime.h>

#define NB 32
#define NS 512
#define NE 128
#define NU 10000

// ---- workspace layout (int units) ----
#define WS_PREVU 0                 // 16384
#define WS_PREVI 16384             // 16384
#define WS_RCNT  32768             // 3*32 per-(round,b) counts
#define WS_LCNT  32864             // 32 per-b late counts
#define WS_GL    32896             // 3*32*512 per-(round,b) t-lists
#define WS_LATE  82048             // 32*512 per-b late t-lists
#define WS_WBF   98432             // 147456 ushorts (bf16 W_stack)

typedef __attribute__((ext_vector_type(8))) short bf16x8;
typedef __attribute__((ext_vector_type(4))) float f32x4;

__device__ __forceinline__ unsigned short f2bf(float f) {
    unsigned int u = __float_as_uint(f);
    u += 0x7fff + ((u >> 16) & 1);   // round-to-nearest-even
    return (unsigned short)(u >> 16);
}

// LDS-only barrier (no vmcnt drain; global loads/stores stay in flight).
#define BARRIER() do { \
    asm volatile("s_waitcnt lgkmcnt(0)" ::: "memory"); \
    __builtin_amdgcn_s_barrier(); \
    __builtin_amdgcn_sched_barrier(0); \
} while (0)

// ---- kernel 1: prep (blocks 0..31) + convw (32..67) — R14-measured ----
__global__ __launch_bounds__(512) void prep_kernel(
    const int* __restrict__ users, const int* __restrict__ items,
    const float* __restrict__ w_ih, const float* __restrict__ w_hh, int* ws)
{
    const int blk = blockIdx.x, tid = threadIdx.x;
    if (blk >= 32) {
        const int base = (blk - 32) * 4096 + tid * 8;
        const int r = base >> 7, k = base & 127;
        const float* src;
        if (r < 384)      src = w_ih + (size_t)r * 256 + k;
        else if (r < 768) src = w_ih + (size_t)(r - 384) * 256 + 128 + k;
        else              src = w_hh + (size_t)(r - 768) * 128 + k;
        unsigned short* wbf = (unsigned short*)(ws + WS_WBF);
#pragma unroll
        for (int j = 0; j < 8; ++j) wbf[base + j] = f2bf(src[j]);
        return;
    }
    const int b = blk;
    __shared__ int s_u[NS], s_i[NS];
    __shared__ unsigned char s_r[NS];
    __shared__ int cnt[3], s_chg;
    s_u[tid] = users[b * NS + tid];
    s_i[tid] = items[b * NS + tid];
    if (tid < 3) cnt[tid] = 0;
    __syncthreads();
    const int mu = s_u[tid], mi = s_i[tid];
    int pu = -1, pi = -1;
    for (int u = tid - 1; u >= 0 && ((pu < 0) | (pi < 0)); u -= 8) {
        int vu[8], vi[8];
#pragma unroll
        for (int j = 0; j < 8; ++j) {
            const int uu = u - j;
            vu[j] = (uu >= 0) ? s_u[uu] : -1;
            vi[j] = (uu >= 0) ? s_i[uu] : -1;
        }
#pragma unroll
        for (int j = 0; j < 8; ++j) {
            if (pu < 0 && vu[j] == mu) pu = u - j;
            if (pi < 0 && vi[j] == mi) pi = u - j;
        }
    }
    ws[WS_PREVU + (b << 9) + tid] = pu;
    ws[WS_PREVI + (b << 9) + tid] = pi;
    s_r[tid] = (pu < 0 && pi < 0) ? 0 : 255;
    __syncthreads();
    for (int pass = 0; pass < 16; ++pass) {
        if (tid == 0) s_chg = 0;
        __syncthreads();
        if (s_r[tid] == 255) {
            const int ru = pu < 0 ? -1 : (int)s_r[pu];
            const int ri = pi < 0 ? -1 : (int)s_r[pi];
            if (ru != 255 && ri != 255) {
                int rr = 1 + (ru > ri ? ru : ri);
                if (rr > 3) rr = 3;
                s_r[tid] = (unsigned char)rr;
                s_chg = 1;
            }
        }
        __syncthreads();
        if (!s_chg) break;
    }
    const int r = s_r[tid];
    if (r < 3) {
        const int slot = atomicAdd(&cnt[r], 1);
        ws[WS_GL + (r * 32 + b) * 512 + slot] = tid;
    }
    __syncthreads();
    if (tid < 3) ws[WS_RCNT + tid * 32 + b] = cnt[tid];
    if (tid == 0) {
        int n = 0;
        for (int t = 0; t < NS; ++t)
            if (s_r[t] >= 3) { ws[WS_LATE + (b << 9) + n] = t; ++n; }
        ws[WS_LCNT + b] = n;
    }
}

// ---- kernel 2: pipelined chunk engine for round r ----
// 256 blocks: b = blk&31, sblk = blk>>5 owns chunks sblk, sblk+8, ...
// Iter i: phase1 {meta(i+2); stage xb(i)} | B | phase2 {gather(i+2) issue;
// MFMA(i) -> yl[i&1]; gates(i-1) <- yl[(i-1)&1], x_old in regs} | B.
// 2 barriers/chunk; MFMA and gates co-issue on separate pipes.
__global__ __launch_bounds__(512, 1) void rg_kernel(
    const int* __restrict__ users, const int* __restrict__ items,
    const float* __restrict__ umem0, const float* __restrict__ imem0,
    const float* __restrict__ b_ih, const float* __restrict__ b_hh,
    const int* __restrict__ ws, float* uout, float* iout, int r)
{
    const int b = blockIdx.x & 31, sblk = blockIdx.x >> 5;
    const int cnt = ws[WS_RCNT + r * 32 + b];
    const int nch = (cnt + 7) >> 3;
    if (sblk >= nch) return;
    const int m = (nch - sblk + 7) >> 3;       // local chunks: lc = sblk+8*i
    const int tid = threadIdx.x;
    const int lane = tid & 63, wave = tid >> 6;
    const int col = lane & 15, kgrp = lane >> 4;

    __shared__ __align__(16) float yl[2][16 * 1156];        // 148.0 KB
    __shared__ __align__(16) unsigned short xb[16 * 136];   // 4.4 KB
    __shared__ __align__(16) float b6[768];                 // 3.0 KB
    __shared__ short sg_list[512];                          // 1.0 KB
    __shared__ short sprev[2][512];                         // 2.0 KB
    __shared__ unsigned long long srcs[4][16];              // 0.5 KB
    __shared__ unsigned long long hdst[4][16];              // 0.5 KB

    for (int i = tid; i < 768; i += 512)
        b6[i] = i < 384 ? b_ih[i] : b_hh[i - 384];
    if (tid < 512) {
        sg_list[tid] = (short)((tid < cnt) ? ws[WS_GL + (r * 32 + b) * 512 + tid] : 0);
        sprev[0][tid] = (short)ws[WS_PREVU + (b << 9) + tid];
        sprev[1][tid] = (short)ws[WS_PREVI + (b << 9) + tid];
    }

    const unsigned short* wbf = (const unsigned short*)(ws + WS_WBF);
    bf16x8 wfrag[9][4];
#pragma unroll
    for (int m9 = 0; m9 < 9; ++m9) {
        const int row = wave * 144 + m9 * 16 + col;
#pragma unroll
        for (int kt = 0; kt < 4; ++kt)
            wfrag[m9][kt] = *(const bf16x8*)&wbf[row * 128 + kt * 32 + kgrp * 8];
    }
    __syncthreads();

    const int gc = tid >> 5;                  // col this thread owns
    const int e4 = (tid & 31) * 4;            // 4-elem group within the col

    // meta for local chunk CI -> slot SLOT (tid<16: 2 cols each of 8 nodes)
#define META(CI, SLOT) do { \
    if (tid < 16) { \
        const int j = (sblk + 8 * (CI)) * 8 + (tid >> 1); \
        unsigned long long sp = 0, hd = 0; \
        if (j < cnt) { \
            const int t = (int)sg_list[j]; \
            const int node = (b << 9) + t; \
            const int cell = tid & 1; \
            const int p = (int)sprev[cell][t]; \
            const float* s; \
            if (p < 0) { \
                const int ix = cell ? items[node] : users[node]; \
                s = (cell ? imem0 : umem0) + ((size_t)b * NU + ix) * NE; \
            } else { \
                s = (cell ? iout : uout) + ((size_t)((b << 9) + p)) * NE; \
            } \
            sp = (unsigned long long)s; \
            hd = (unsigned long long)((cell ? iout : uout) + (size_t)node * NE); \
        } \
        srcs[SLOT][tid] = sp; hdst[SLOT][tid] = hd; \
    } \
} while (0)

    // gates for chunk with yl parity P, x_old VP, dest slot DS
#define GATES(P, VP, DS) do { \
    const float* hb = (const float*)hdst[DS][gc]; \
    if (hb) { \
        const float* ys = &yl[P][gc * 1156]; \
        const float* yo = &yl[P][(gc ^ 1) * 1156]; \
        const float4 yir = *(const float4*)&ys[e4]; \
        const float4 yiz = *(const float4*)&ys[128 + e4]; \
        const float4 yin = *(const float4*)&ys[256 + e4]; \
        const float4 oir = *(const float4*)&yo[384 + e4]; \
        const float4 oiz = *(const float4*)&yo[512 + e4]; \
        const float4 oin = *(const float4*)&yo[640 + e4]; \
        const float4 yhr = *(const float4*)&ys[768 + e4]; \
        const float4 yhz = *(const float4*)&ys[896 + e4]; \
        const float4 yhn = *(const float4*)&ys[1024 + e4]; \
        const float4 bir = *(const float4*)&b6[e4]; \
        const float4 biz = *(const float4*)&b6[128 + e4]; \
        const float4 bin = *(const float4*)&b6[256 + e4]; \
        const float4 bhr = *(const float4*)&b6[384 + e4]; \
        const float4 bhz = *(const float4*)&b6[512 + e4]; \
        const float4 bhn = *(const float4*)&b6[640 + e4]; \
        float4 hout; \
        _Pragma("unroll") \
        for (int jj = 0; jj < 4; ++jj) { \
            const float gir = ((const float*)&yir)[jj] + ((const float*)&oir)[jj] + ((const float*)&bir)[jj]; \
            const float giz = ((const float*)&yiz)[jj] + ((const float*)&oiz)[jj] + ((const float*)&biz)[jj]; \
            const float gin = ((const float*)&yin)[jj] + ((const float*)&oin)[jj] + ((const float*)&bin)[jj]; \
            const float ghr = ((const float*)&yhr)[jj] + ((const float*)&bhr)[jj]; \
            const float ghz = ((const float*)&yhz)[jj] + ((const float*)&bhz)[jj]; \
            const float ghn = ((const float*)&yhn)[jj] + ((const float*)&bhn)[jj]; \
            const float rr = 1.f / (1.f + __expf(-(gir + ghr))); \
            const float z  = 1.f / (1.f + __expf(-(giz + ghz))); \
            const float pre = gin + rr * ghn; \
            const float nn = 2.f / (1.f + __expf(-2.f * pre)) - 1.f; \
            ((float*)&hout)[jj] = (1.f - z) * nn + z * ((const float*)&(VP))[jj]; \
        } \
        *(float4*)((float*)hb + e4) = hout; \
    } \
} while (0)

    // ---- prologue: metas for chunks 0,1; gathers for both ----
    META(0, 0);
    META(1, 1);
    BARRIER();
    float4 vs = (float4){0.f, 0.f, 0.f, 0.f};   // chunk i   (stage next)
    float4 vg = (float4){0.f, 0.f, 0.f, 0.f};   // chunk i+1 (in flight)
    float4 vp = (float4){0.f, 0.f, 0.f, 0.f};   // chunk i-1 (gates)
    {
        const float* s0 = (const float*)srcs[0][gc];
        if (s0) vs = *(const float4*)(s0 + e4);
        if (1 < m) {
            const float* s1 = (const float*)srcs[1][gc];
            if (s1) vg = *(const float4*)(s1 + e4);
        }
    }

    for (int i = 0; i < m; ++i) {
        // ---- phase1: meta(i+2); stage xb(i) ----
        if (i + 2 < m) META(i + 2, (i + 2) & 3);
        {
            ushort4 w4;
            w4.x = f2bf(vs.x); w4.y = f2bf(vs.y);
            w4.z = f2bf(vs.z); w4.w = f2bf(vs.w);
            *(ushort4*)&xb[gc * 136 + e4] = w4;
        }
        BARRIER();
        // ---- phase2: issue gather(i+2); MFMA(i); gates(i-1) ----
        float4 vgn = (float4){0.f, 0.f, 0.f, 0.f};
        if (i + 2 < m) {
            const float* s = (const float*)srcs[(i + 2) & 3][gc];
            if (s) vgn = *(const float4*)(s + e4);
        }
        {
            bf16x8 bfrag[4];
#pragma unroll
            for (int kt = 0; kt < 4; ++kt)
                bfrag[kt] = *(const bf16x8*)&xb[col * 136 + kt * 32 + kgrp * 8];
            f32x4 acc[9];
#pragma unroll
            for (int m9 = 0; m9 < 9; ++m9) acc[m9] = (f32x4){0.f, 0.f, 0.f, 0.f};
#pragma unroll
            for (int kt = 0; kt < 4; ++kt)
#pragma unroll
                for (int m9 = 0; m9 < 9; ++m9)
                    acc[m9] = __builtin_amdgcn_mfma_f32_16x16x32_bf16(
                        wfrag[m9][kt], bfrag[kt], acc[m9], 0, 0, 0);
            float* ybase = &yl[i & 1][col * 1156 + wave * 144 + kgrp * 4];
#pragma unroll
            for (int m9 = 0; m9 < 9; ++m9)   // D: col=lane&15, row=kgrp*4+reg
                *(f32x4*)(ybase + m9 * 16) = acc[m9];
        }
        if (i >= 1) GATES((i - 1) & 1, vp, (i - 1) & 3);
        BARRIER();
        vp = vs; vs = vg; vg = vgn;
    }
    // ---- epilogue: gates for last chunk ----
    GATES((m - 1) & 1, vp, (m - 1) & 3);
#undef META
#undef GATES
}

// ---- kernel 3: cleanup — r2 chunks + late singles, per b (R14-measured) ----
__global__ __launch_bounds__(512, 1) void cleanup_kernel(
    const int* __restrict__ users, const int* __restrict__ items,
    const float* __restrict__ umem0, const float* __restrict__ imem0,
    const float* __restrict__ b_ih, const float* __restrict__ b_hh,
    const int* __restrict__ ws, float* uout, float* iout)
{
    const int b = blockIdx.x;
    const int cnt2 = ws[WS_RCNT + 64 + b];
    const int cntL = ws[WS_LCNT + b];
    if (cnt2 + cntL == 0) return;
    const int tid = threadIdx.x;
    const int lane = tid & 63, wave = tid >> 6;
    const int col = lane & 15, kgrp = lane >> 4;

    __shared__ __align__(16) float yl[16 * 1156];
    __shared__ __align__(16) float xf[16 * 132];
    __shared__ __align__(16) unsigned short xb[16 * 136];
    __shared__ float b6[768];
    __shared__ unsigned long long srcs[16];
    __shared__ unsigned long long hdst[16];

    for (int i = tid; i < 768; i += 512)
        b6[i] = i < 384 ? b_ih[i] : b_hh[i - 384];

    const unsigned short* wbf = (const unsigned short*)(ws + WS_WBF);
    bf16x8 wfrag[9][4];
#pragma unroll
    for (int m9 = 0; m9 < 9; ++m9) {
        const int row = wave * 144 + m9 * 16 + col;
#pragma unroll
        for (int kt = 0; kt < 4; ++kt)
            wfrag[m9][kt] = *(const bf16x8*)&wbf[row * 128 + kt * 32 + kgrp * 8];
    }

    const int* prevU = ws + WS_PREVU + (b << 9);
    const int* prevI = ws + WS_PREVI + (b << 9);

    for (int ph = 0; ph < 2; ++ph) {
        const int cntn = ph == 0 ? cnt2 : cntL;
        const int* lst = ph == 0 ? ws + WS_GL + (64 + b) * 512
                                 : ws + WS_LATE + (b << 9);
        const int step = ph == 0 ? 8 : 1;
        for (int j0 = 0; j0 < cntn; j0 += step) {
            const int n = (cntn - j0 < step) ? (cntn - j0) : step;
            if (tid < 16) {
                const int jj = tid >> 1;
                unsigned long long sp = 0, hd = 0;
                if (jj < n) {
                    const int t = lst[j0 + jj];
                    const int node = (b << 9) + t;
                    const int cell = tid & 1;
                    const int p = cell ? prevI[t] : prevU[t];
                    const float* s;
                    if (p < 0) {
                        const int ix = cell ? items[node] : users[node];
                        s = (cell ? imem0 : umem0) + ((size_t)b * NU + ix) * NE;
                    } else {
                        s = (cell ? iout : uout) + ((size_t)((b << 9) + p)) * NE;
                    }
                    sp = (unsigned long long)s;
                    hd = (unsigned long long)((cell ? iout : uout) + (size_t)node * NE);
                }
                srcs[tid] = sp; hdst[tid] = hd;
            }
            __syncthreads();
            {
                const int c = tid >> 5, ee = (tid & 31) * 4;
                const float* s = (const float*)srcs[c];
                if (s) {
                    const float4 vv = *(const float4*)(s + ee);
                    *(float4*)&xf[c * 132 + ee] = vv;
                    ushort4 w4;
                    w4.x = f2bf(vv.x); w4.y = f2bf(vv.y);
                    w4.z = f2bf(vv.z); w4.w = f2bf(vv.w);
                    *(ushort4*)&xb[c * 136 + ee] = w4;
                }
            }
            __syncthreads();
            {
                bf16x8 bfrag[4];
#pragma unroll
                for (int kt = 0; kt < 4; ++kt)
                    bfrag[kt] = *(const bf16x8*)&xb[col * 136 + kt * 32 + kgrp * 8];
                f32x4 acc[9];
#pragma unroll
                for (int m9 = 0; m9 < 9; ++m9) acc[m9] = (f32x4){0.f, 0.f, 0.f, 0.f};
#pragma unroll
                for (int kt = 0; kt < 4; ++kt)
#pragma unroll
                    for (int m9 = 0; m9 < 9; ++m9)
                        acc[m9] = __builtin_amdgcn_mfma_f32_16x16x32_bf16(
                            wfrag[m9][kt], bfrag[kt], acc[m9], 0, 0, 0);
#pragma unroll
                for (int m9 = 0; m9 < 9; ++m9)
                    *(f32x4*)&yl[col * 1156 + wave * 144 + m9 * 16 + kgrp * 4] = acc[m9];
            }
            __syncthreads();
#pragma unroll
            for (int it = 0; it < 4; ++it) {
                const int idx = tid + it * 512;
                const int c = idx >> 7, e = idx & 127;
                float* hb = (float*)hdst[c];
                if (hb) {
                    const float* ys = &yl[c * 1156];
                    const float* yo = &yl[(c ^ 1) * 1156];
                    const float gir = ys[e]        + yo[384 + e] + b6[e];
                    const float giz = ys[128 + e]  + yo[512 + e] + b6[128 + e];
                    const float gin = ys[256 + e]  + yo[640 + e] + b6[256 + e];
                    const float ghr = ys[768 + e]  + b6[384 + e];
                    const float ghz = ys[896 + e]  + b6[512 + e];
                    const float ghn = ys[1024 + e] + b6[640 + e];
                    const float rr = 1.f / (1.f + __expf(-(gir + ghr)));
                    const float z  = 1.f / (1.f + __expf(-(giz + ghz)));
                    const float pre = gin + rr * ghn;
                    const float nn = 2.f / (1.f + __expf(-2.f * pre)) - 1.f;
                    hb[e] = (1.f - z) * nn + z * xf[c * 132 + e];
                }
            }
            __threadfence();
            __syncthreads();
        }
    }
}

extern "C" void kernel_launch(void* const* d_in, const int* in_sizes, int n_in,
                              void* d_out, int out_size, void* d_ws, size_t ws_size,
                              hipStream_t stream) {
    const int*   users = (const int*)d_in[0];
    const int*   items = (const int*)d_in[1];
    const float* umem0 = (const float*)d_in[2];
    const float* imem0 = (const float*)d_in[3];
    const float* w_ih  = (const float*)d_in[4];
    const float* w_hh  = (const float*)d_in[5];
    const float* b_ih  = (const float*)d_in[6];
    const float* b_hh  = (const float*)d_in[7];

    float* uout = (float*)d_out;
    float* iout = uout + (size_t)NB * NS * NE;
    int* ws = (int*)d_ws;

    prep_kernel<<<68, 512, 0, stream>>>(users, items, w_ih, w_hh, ws);
    rg_kernel<<<256, 512, 0, stream>>>(users, items, umem0, imem0,
                                       b_ih, b_hh, ws, uout, iout, 0);
    rg_kernel<<<256, 512, 0, stream>>>(users, items, umem0, imem0,
                                       b_ih, b_hh, ws, uout, iout, 1);
    cleanup_kernel<<<NB, 512, 0, stream>>>(users, items, umem0, imem0,
                                           b_ih, b_hh, ws, uout, iout);
}